// Round 15
// baseline (80.137 us; speedup 1.0000x reference)
//
#include <hip/hip_runtime.h>

typedef __bf16 bf16;
typedef __bf16 bf16x8 __attribute__((ext_vector_type(8)));
typedef __bf16 bf16x4 __attribute__((ext_vector_type(4)));
typedef float  f32x4  __attribute__((ext_vector_type(4)));

static constexpr int NB = 8;      // batch
static constexpr int NH = 12;     // heads
static constexpr int HD = 32;     // head dim
static constexpr int NN = 1024;   // tokens (32x32)
static constexpr int NC = 384;    // channels

static constexpr float LOG2E = 1.4426950408889634f;
static constexpr float QSC   = (float)(0.17677669529663687 * 1.4426950408889634); // scale*log2e

static constexpr size_t WP_N   = (size_t)NC*NC;
static constexpr size_t QKV_N  = (size_t)NB*NH*NN*HD;
static constexpr size_t AO_N   = (size_t)NB*NN*NC;

static constexpr size_t WP_OFF   = 0;
static constexpr size_t Q_OFF    = WP_OFF + WP_N;
static constexpr size_t K_OFF    = Q_OFF + QKV_N;
static constexpr size_t V_OFF    = K_OFF + QKV_N;
static constexpr size_t AO_OFF   = V_OFF + QKV_N;     // [b][n][c] bf16
static constexpr size_t PT_OFF   = AO_OFF + AO_N;     // u32 pair-table, bf16-elem offset

static constexpr int PT_PER_H = 63 * 62;              // [dj][dip] per head
static constexpr int PT_TOTAL = NH * PT_PER_H;        // 46872 u32

#define MFMA16(a,b,c) __builtin_amdgcn_mfma_f32_16x16x32_bf16(a,b,c,0,0,0)

static __device__ inline float fast_exp2(float x) {
#if __has_builtin(__builtin_amdgcn_exp2f)
    return __builtin_amdgcn_exp2f(x);
#else
    return exp2f(x);
#endif
}

// ---------------- small cast: wproj + bias pair-table (x-cast now fused into qkv) ----
__global__ __launch_bounds__(256) void cast_pt_kernel(const float* __restrict__ wproj,
                                                      const float* __restrict__ bias_table,
                                                      bf16* __restrict__ wp,
                                                      unsigned* __restrict__ PT)
{
    const int t = threadIdx.x;
    if (blockIdx.x < 144) {
        const size_t i = ((size_t)blockIdx.x * 256 + t) * 4;
        if (i >= WP_N) return;
        float4 v = *(const float4*)(wproj + i);
        bf16x4 o; o[0] = (bf16)v.x; o[1] = (bf16)v.y; o[2] = (bf16)v.z; o[3] = (bf16)v.w;
        *(bf16x4*)(wp + i) = o;
        return;
    }
    const int e = (blockIdx.x - 144) * 256 + t;
    if (e >= PT_TOTAL) return;
    const int h = e / PT_PER_H, rem = e - h * PT_PER_H;
    const int dj = rem / 62, dip = rem - dj * 62;
    bf16 lo = (bf16)(bias_table[(size_t)((dip + 1) * 63 + dj) * NH + h] * LOG2E);
    bf16 hi = (bf16)(bias_table[(size_t)(dip * 63 + dj) * NH + h] * LOG2E);
    PT[e] = (unsigned)__builtin_bit_cast(unsigned short, lo)
          | ((unsigned)__builtin_bit_cast(unsigned short, hi) << 16);
}

// ---------------- QKV projection GEMM: fused f32 cast + transpose staging ----------
// Reads x [b][c][n] f32 and wq/wkv f32 DIRECTLY (no Xt materialization).
// B-tile: 8 coalesced float4 loads (8 k-rows x 4 n) -> in-register transpose ->
// 4 ds_write_b128 into Bs[n][c]. A-tile: 8 float4 along c -> 4 b128 (no transpose).
// 1D grid 576, XCD-swizzled so the 9 o-tiles of one n-tile share an XCD's L2.
// MFMA core + epilogue identical to r12 (verified).
__global__ __launch_bounds__(256) void qkv_gemm_kernel(
    const float* __restrict__ wq, const float* __restrict__ wkv,
    const float* __restrict__ x,
    const float* __restrict__ bq, const float* __restrict__ bkv,
    bf16* __restrict__ Qd, bf16* __restrict__ Kd, bf16* __restrict__ Vd)
{
    __shared__ bf16 As[128][72];   // [o][c]
    __shared__ bf16 Bs[128][72];   // [n][c]
    const int t = threadIdx.x;
    const int w = t >> 6, lane = t & 63, g = lane >> 4, l16 = lane & 15;
    const int wm = w >> 1, wn = w & 1;

    const int wgid = (blockIdx.x & 7) * 72 + (blockIdx.x >> 3);
    const int nt = wgid / 9, ot = wgid - nt * 9;
    const int n0g = nt * 128;
    const int b = n0g >> 10, n0 = n0g & 1023;
    const int o0 = ot * 128;
    const float* Wsrc = (o0 < 384) ? (wq + (size_t)o0 * NC)
                                   : (wkv + (size_t)(o0 - 384) * NC);
    const float* Xb = x + (size_t)b * NC * NN;   // [c][n]

    const int sr = t >> 1, sc2 = (t & 1) * 32;   // A: row, col-half
    const int nq = t & 31, kg = t >> 5;          // B: n-quad, k-octet

    f32x4 acc[4][4] = {};

    float4 af[8], bx[8];
#pragma unroll
    for (int u = 0; u < 8; ++u)
        af[u] = *(const float4*)&Wsrc[(size_t)sr * NC + sc2 + 4*u];
#pragma unroll
    for (int j = 0; j < 8; ++j)
        bx[j] = *(const float4*)&Xb[(size_t)(kg*8 + j) * NN + n0 + nq*4];

    for (int k0 = 0; k0 < NC; k0 += 64) {
        __syncthreads();                 // B0: prev tile reads done
#pragma unroll
        for (int i = 0; i < 4; ++i) {    // A: pack 2 float4 -> bf16x8
            bf16x8 v;
            v[0] = (bf16)af[2*i].x;   v[1] = (bf16)af[2*i].y;
            v[2] = (bf16)af[2*i].z;   v[3] = (bf16)af[2*i].w;
            v[4] = (bf16)af[2*i+1].x; v[5] = (bf16)af[2*i+1].y;
            v[6] = (bf16)af[2*i+1].z; v[7] = (bf16)af[2*i+1].w;
            *(bf16x8*)&As[sr][sc2 + 8*i] = v;
        }
#pragma unroll
        for (int i = 0; i < 4; ++i) {    // B: transpose 8k x 4n in registers
            bf16x8 v;
#pragma unroll
            for (int j = 0; j < 8; ++j) v[j] = (bf16)((&bx[j].x)[i]);
            *(bf16x8*)&Bs[nq*4 + i][kg*8] = v;
        }
        __syncthreads();                 // B1: tile visible
        if (k0 + 64 < NC) {              // early-issue next k-tile (hides under MFMA)
#pragma unroll
            for (int u = 0; u < 8; ++u)
                af[u] = *(const float4*)&Wsrc[(size_t)sr * NC + k0 + 64 + sc2 + 4*u];
#pragma unroll
            for (int j = 0; j < 8; ++j)
                bx[j] = *(const float4*)&Xb[(size_t)(k0 + 64 + kg*8 + j) * NN + n0 + nq*4];
        }
#pragma unroll
        for (int ks = 0; ks < 2; ++ks) {
            bf16x8 a[4], bb[4];
#pragma unroll
            for (int s = 0; s < 4; ++s) {
                a[s]  = *(const bf16x8*)&As[wm*64 + s*16 + l16][ks*32 + g*8];
                bb[s] = *(const bf16x8*)&Bs[wn*64 + s*16 + l16][ks*32 + g*8];
            }
#pragma unroll
            for (int sm = 0; sm < 4; ++sm)
#pragma unroll
                for (int sn = 0; sn < 4; ++sn)
                    acc[sm][sn] = MFMA16(a[sm], bb[sn], acc[sm][sn]);
        }
    }

#pragma unroll
    for (int sm = 0; sm < 4; ++sm)
#pragma unroll
    for (int sn = 0; sn < 4; ++sn) {
        const int col   = n0 + wn*64 + sn*16 + l16;
        const int obase = o0 + wm*64 + sm*16 + g*4;
        f32x4 v = acc[sm][sn];
        if (obase < 384) {
            const int hh = obase >> 5, d = obase & 31;
            bf16x4 o4;
#pragma unroll
            for (int r = 0; r < 4; ++r) o4[r] = (bf16)((v[r] + bq[obase + r]) * QSC);
            *(bf16x4*)&Qd[(((size_t)b*NH + hh)*NN + col)*HD + d] = o4;
        } else if (obase < 768) {
            const int oo = obase - 384; const int hh = oo >> 5, d = oo & 31;
            bf16x4 o4;
#pragma unroll
            for (int r = 0; r < 4; ++r) o4[r] = (bf16)(v[r] + bkv[oo + r]);
            *(bf16x4*)&Kd[(((size_t)b*NH + hh)*NN + col)*HD + d] = o4;
        } else {
            const int oo = obase - 768; const int hh = oo >> 5, d = oo & 31;
#pragma unroll
            for (int r = 0; r < 4; ++r)
                Vd[(((size_t)b*NH + hh)*HD + d + r)*NN + col] = (bf16)(v[r] + bkv[obase - 384 + r]);
        }
    }
}

// ---------------- fused flash attention: split-K, 8 waves x 32 q-rows (r12 verbatim) ----
__global__ __launch_bounds__(512, 3) void attn_kernel(
    const bf16* __restrict__ Qg, const bf16* __restrict__ Kg, const bf16* __restrict__ Vg,
    const unsigned* __restrict__ PT, bf16* __restrict__ AOt)
{
    __shared__ __align__(16) char arena[47488];
    bf16 (*KsH)[128][40]   = (bf16 (*)[128][40])arena;             // [half][m][d], 20480B
    bf16 (*VsH)[2][32][72] = (bf16 (*)[2][32][72])(arena + 20480); // [half][sub][d][q], 18432B
    unsigned (*pairTw)[34] = (unsigned (*)[34])(arena + 38912);    // [63][34], 8568B

    const int t = threadIdx.x;
    const int w = t >> 6, lane = t & 63, g = lane >> 4, l16 = lane & 15;
    const int wl = w & 3, hf = w >> 2;

    // XCD-aware swizzle: 768 blocks, 8 XCDs
    const int bid = blockIdx.x;
    const int nid = (bid & 7) * 96 + (bid >> 3);
    const int qt = nid & 7;
    const int hb = nid >> 3;
    const int h = hb % 12, b = hb / 12;

    const bf16* Qb = Qg + ((size_t)(b*NH + h)) * NN * HD;
    const bf16* Kb = Kg + ((size_t)(b*NH + h)) * NN * HD;
    const bf16* Vb = Vg + ((size_t)(b*NH + h)) * HD * NN;

    // staging slots within 256-thread group g2 (== hf for the compute waves)
    const int tl = t & 255, g2 = t >> 8;
    const int kr = tl >> 1, kc2 = (tl & 1) * 16;
    const int vd = tl >> 3, vmb = (tl & 7) * 16;
    int vsub[2], vqa[2];
#pragma unroll
    for (int i = 0; i < 2; ++i) {
        const int vm = vmb + 8*i, vmm = vm & 63;
        vsub[i] = vm >> 6;
        vqa[i]  = ((vmm >> 5) & 1) * 32 + ((vmm >> 2) & 3) * 8 + ((vmm >> 4) & 1) * 4;
    }
    const int mbase = g2 * 512;

    // issue phase-0 loads first (latency hides under pair-table staging)
    bf16x8 sregK[2], sregV[2];
#pragma unroll
    for (int i = 0; i < 2; ++i) {
        sregK[i] = *(const bf16x8*)&Kb[(size_t)(mbase + kr) * HD + kc2 + 8*i];
        sregV[i] = *(const bf16x8*)&Vb[(size_t)vd * NN + mbase + vmb + 8*i];
    }

    const int q0 = qt * 128;
    const bf16x8 qfrag0 = *(const bf16x8*)&Qb[(size_t)(q0 + wl*32      + l16) * HD + g*8];
    const bf16x8 qfrag1 = *(const bf16x8*)&Qb[(size_t)(q0 + wl*32 + 16 + l16) * HD + g*8];

    // stage the precomputed pair-table window (coalesced b32 loads)
    const unsigned* PTh = PT + (size_t)h * PT_PER_H + 4 * qt;
    for (int idx = t; idx < 63 * 34; idx += 512) {
        const int dj = idx / 34, dipl = idx - dj * 34;
        pairTw[dj][dipl] = PTh[dj * 62 + dipl];
    }
    // visible after the loop's first two barriers

    const unsigned* twp = &pairTw[0][0];
    const int rowD1 = (l16 + 31 - 4*g) * 34;

    bf16x8 vones;
#pragma unroll
    for (int e = 0; e < 8; ++e) vones[e] = (bf16)1.0f;

    f32x4 oacc0[2] = {}, oacc1[2] = {};
    f32x4 oacc_l0 = {}, oacc_l1 = {};

    for (int ph = 0; ph < 4; ++ph) {
        __syncthreads();                              // B0: all reads of prev phase done
#pragma unroll
        for (int i = 0; i < 2; ++i) {
            *(bf16x8*)&KsH[g2][kr][kc2 + 8*i] = sregK[i];
            bf16x4 vlo = __builtin_shufflevector(sregV[i], sregV[i], 0, 1, 2, 3);
            bf16x4 vhi = __builtin_shufflevector(sregV[i], sregV[i], 4, 5, 6, 7);
            *(bf16x4*)&VsH[g2][vsub[i]][vd][vqa[i]]     = vlo;
            *(bf16x4*)&VsH[g2][vsub[i]][vd][vqa[i] + 8] = vhi;
        }
        __syncthreads();                              // B1: phase tiles visible
        if (ph < 3) {                                 // T14: issue next phase early
            const int m1 = mbase + (ph + 1) * 128;
#pragma unroll
            for (int i = 0; i < 2; ++i) {
                sregK[i] = *(const bf16x8*)&Kb[(size_t)(m1 + kr) * HD + kc2 + 8*i];
                sregV[i] = *(const bf16x8*)&Vb[(size_t)vd * NN + m1 + vmb + 8*i];
            }
        }

#pragma unroll
        for (int sub = 0; sub < 2; ++sub) {
            const int it = hf * 8 + 2 * ph + sub;     // global 64-key subtile index
            const bf16 (*Vsp)[72] = VsH[hf][sub];
            const int dipl = wl + 30 - 2*it;          // in [0,33]
            const unsigned* pD1 = twp + rowD1 + dipl;

            // shared bias rows: D0 = D1-16 rows, D2 = D1+16 rows (stride 34 u32)
            f32x4 b00, b01, b02, b03, b10, b12;       // b11=b00, b13=b02
#pragma unroll
            for (int r = 0; r < 4; ++r) {
                const unsigned d1w = pD1[-34 * r];
                const unsigned d0w = pD1[-34 * r - 544];
                const unsigned d2w = pD1[-34 * r + 544];
                b00[r] = __uint_as_float(d1w << 16);
                b02[r] = __uint_as_float(d1w & 0xFFFF0000u);
                b01[r] = __uint_as_float(d0w << 16);
                b03[r] = __uint_as_float(d0w & 0xFFFF0000u);
                b10[r] = __uint_as_float(d2w << 16);
                b12[r] = __uint_as_float(d2w & 0xFFFF0000u);
            }
            f32x4 bacc0[4] = {b00, b01, b02, b03};
            f32x4 bacc1[4] = {b10, b00, b12, b02};

            bf16x8 pa0[2], pa1[2];
#pragma unroll
            for (int sc = 0; sc < 4; ++sc) {
                bf16x8 kf = *(const bf16x8*)&KsH[hf][sub*64 + sc*16 + l16][g*8];
                f32x4 z0 = MFMA16(kf, qfrag0, bacc0[sc]);   // S^T + bias, frag0
                f32x4 z1 = MFMA16(kf, qfrag1, bacc1[sc]);   // frag1
                const int kc = sc >> 1, hl = (sc & 1) * 4;
#pragma unroll
                for (int r = 0; r < 4; ++r) {
                    pa0[kc][hl + r] = (bf16)fast_exp2(z0[r]);
                    pa1[kc][hl + r] = (bf16)fast_exp2(z1[r]);
                }
            }

            // PV: slot k=8g+4sh+r <-> m=32kc+16sh+4g+r ; vf shared across frags
#pragma unroll
            for (int kc = 0; kc < 2; ++kc) {
#pragma unroll
                for (int ds = 0; ds < 2; ++ds) {
                    bf16x8 vf = *(const bf16x8*)&Vsp[ds*16 + l16][kc*32 + 8*g];
                    oacc0[ds] = MFMA16(pa0[kc], vf, oacc0[ds]);
                    oacc1[ds] = MFMA16(pa1[kc], vf, oacc1[ds]);
                }
                oacc_l0 = MFMA16(pa0[kc], vones, oacc_l0);
                oacc_l1 = MFMA16(pa1[kc], vones, oacc_l1);
            }
        }
    }

    // merge halves: waves 4-7 publish partials; waves 0-3 combine + epilogue
    __syncthreads();                                  // all LDS reads of last phase done
    f32x4* mbuf = (f32x4*)arena;                      // 6 x [4][64] f32x4 = 24576B
    const int sb = wl * 64 + lane;
    if (hf == 1) {
        mbuf[0*256 + sb] = oacc0[0]; mbuf[1*256 + sb] = oacc0[1];
        mbuf[2*256 + sb] = oacc1[0]; mbuf[3*256 + sb] = oacc1[1];
        mbuf[4*256 + sb] = oacc_l0;  mbuf[5*256 + sb] = oacc_l1;
    }
    __syncthreads();
    if (hf == 0) {
        oacc0[0] += mbuf[0*256 + sb]; oacc0[1] += mbuf[1*256 + sb];
        oacc1[0] += mbuf[2*256 + sb]; oacc1[1] += mbuf[3*256 + sb];
        oacc_l0  += mbuf[4*256 + sb]; oacc_l1  += mbuf[5*256 + sb];

        float rin0[4], rin1[4];
#pragma unroll
        for (int r = 0; r < 4; ++r) {
            rin0[r] = 1.0f / oacc_l0[r];
            rin1[r] = 1.0f / oacc_l1[r];
        }
        const int nrow0 = q0 + wl*32 + g*4;
#pragma unroll
        for (int ds = 0; ds < 2; ++ds) {
            const int c = h*HD + ds*16 + l16;
#pragma unroll
            for (int r = 0; r < 4; ++r) {
                AOt[((size_t)b*NN + nrow0 + r)      * NC + c] = (bf16)(oacc0[ds][r] * rin0[r]);
                AOt[((size_t)b*NN + nrow0 + 16 + r) * NC + c] = (bf16)(oacc1[ds][r] * rin1[r]);
            }
        }
    }
}

// ---------------- output projection GEMM (64x128 tile, reg-prefetch; r12 verbatim) ----
__global__ __launch_bounds__(256) void proj_gemm_kernel(
    const bf16* __restrict__ W, const bf16* __restrict__ AOt,
    const float* __restrict__ bproj, float* __restrict__ out)
{
    __shared__ bf16 As[64][40];
    __shared__ bf16 Bs[128][40];
    const int t = threadIdx.x;
    const int w = t >> 6, lane = t & 63, g = lane >> 4, l16 = lane & 15;
    const int wm = w >> 1, wn = w & 1;
    const int n0g = blockIdx.x * 128;
    const int b = n0g >> 10, n0 = n0g & 1023;
    const int o0 = blockIdx.y * 64;
    const bf16* Ab = AOt + (size_t)b * NN * NC;

    const int ar = t >> 2, ac = (t & 3) * 8;

    f32x4 acc[2][4] = {};

    bf16x8 aw = *(const bf16x8*)&W[(size_t)(o0 + ar) * NC + ac];
    bf16x8 bw[2];
#pragma unroll
    for (int i = 0; i < 2; ++i) {
        const int s = t + i * 256, r = s >> 2, cc = (s & 3) * 8;
        bw[i] = *(const bf16x8*)&Ab[(size_t)(n0 + r) * NC + cc];
    }

    for (int k0 = 0; k0 < NC; k0 += 32) {
        __syncthreads();
        *(bf16x8*)&As[ar][ac] = aw;
#pragma unroll
        for (int i = 0; i < 2; ++i) {
            const int s = t + i * 256, r = s >> 2, cc = (s & 3) * 8;
            *(bf16x8*)&Bs[r][cc] = bw[i];
        }
        __syncthreads();
        if (k0 + 32 < NC) {
            aw = *(const bf16x8*)&W[(size_t)(o0 + ar) * NC + k0 + 32 + ac];
#pragma unroll
            for (int i = 0; i < 2; ++i) {
                const int s = t + i * 256, r = s >> 2, cc = (s & 3) * 8;
                bw[i] = *(const bf16x8*)&Ab[(size_t)(n0 + r) * NC + k0 + 32 + cc];
            }
        }
        bf16x8 a0 = *(const bf16x8*)&As[wm*32      + l16][g*8];
        bf16x8 a1 = *(const bf16x8*)&As[wm*32 + 16 + l16][g*8];
#pragma unroll
        for (int sn = 0; sn < 4; ++sn) {
            bf16x8 bf = *(const bf16x8*)&Bs[wn*64 + sn*16 + l16][g*8];
            acc[0][sn] = MFMA16(a0, bf, acc[0][sn]);
            acc[1][sn] = MFMA16(a1, bf, acc[1][sn]);
        }
    }

#pragma unroll
    for (int sm = 0; sm < 2; ++sm)
#pragma unroll
    for (int sn = 0; sn < 4; ++sn) {
        const int col   = n0 + wn*64 + sn*16 + l16;
        const int obase = o0 + wm*32 + sm*16 + g*4;
        f32x4 v = acc[sm][sn];
#pragma unroll
        for (int r = 0; r < 4; ++r)
            out[((size_t)b*NC + obase + r)*NN + col] = v[r] + bproj[obase + r];
    }
}

extern "C" void kernel_launch(void* const* d_in, const int* in_sizes, int n_in,
                              void* d_out, int out_size, void* d_ws, size_t ws_size,
                              hipStream_t stream)
{
    const float* x          = (const float*)d_in[0];
    const float* wq         = (const float*)d_in[1];
    const float* bq         = (const float*)d_in[2];
    const float* wkv        = (const float*)d_in[3];
    const float* bkv        = (const float*)d_in[4];
    const float* wproj      = (const float*)d_in[5];
    const float* bproj      = (const float*)d_in[6];
    const float* bias_table = (const float*)d_in[7];
    // d_in[8] = rel_index: unused (bias index computed arithmetically in-kernel)
    float* out = (float*)d_out;

    bf16* wsb  = (bf16*)d_ws;
    bf16* Wp   = wsb + WP_OFF;
    bf16* Qd   = wsb + Q_OFF;
    bf16* Kd   = wsb + K_OFF;
    bf16* Vd   = wsb + V_OFF;
    bf16* AOt  = wsb + AO_OFF;
    unsigned* PT = (unsigned*)(wsb + PT_OFF);

    const int ptBlocks = (PT_TOTAL + 255) / 256;       // 184
    cast_pt_kernel<<<dim3(144 + ptBlocks), 256, 0, stream>>>(wproj, bias_table, Wp, PT);
    qkv_gemm_kernel<<<dim3(576), 256, 0, stream>>>(wq, wkv, x, bq, bkv, Qd, Kd, Vd);
    attn_kernel<<<dim3(768), 512, 0, stream>>>(Qd, Kd, Vd, PT, AOt);
    proj_gemm_kernel<<<dim3(64, 6), 256, 0, stream>>>(Wp, AOt, bproj, out);
}

// Round 16
// 63.673 us; speedup vs baseline: 1.2586x; 1.2586x over previous
//
#include <hip/hip_runtime.h>

typedef __bf16 bf16;
typedef __bf16 bf16x8 __attribute__((ext_vector_type(8)));
typedef __bf16 bf16x4 __attribute__((ext_vector_type(4)));
typedef float  f32x4  __attribute__((ext_vector_type(4)));

static constexpr int NB = 8;      // batch
static constexpr int NH = 12;     // heads
static constexpr int HD = 32;     // head dim
static constexpr int NN = 1024;   // tokens (32x32)
static constexpr int NC = 384;    // channels

static constexpr float LOG2E = 1.4426950408889634f;
static constexpr float QSC   = (float)(0.17677669529663687 * 1.4426950408889634); // scale*log2e

static constexpr size_t XT_N   = (size_t)NB*NN*NC;    // x transposed [b][n][c] bf16
static constexpr size_t WQKV_N = (size_t)3*NC*NC;
static constexpr size_t WP_N   = (size_t)NC*NC;
static constexpr size_t QKV_N  = (size_t)NB*NH*NN*HD;
static constexpr size_t AO_N   = (size_t)NB*NN*NC;

static constexpr size_t XT_OFF   = 0;
static constexpr size_t WQKV_OFF = XT_OFF + XT_N;
static constexpr size_t WP_OFF   = WQKV_OFF + WQKV_N;
static constexpr size_t Q_OFF    = WP_OFF + WP_N;
static constexpr size_t K_OFF    = Q_OFF + QKV_N;
static constexpr size_t V_OFF    = K_OFF + QKV_N;
static constexpr size_t AO_OFF   = V_OFF + QKV_N;     // [b][n][c] bf16
static constexpr size_t PT_OFF   = AO_OFF + AO_N;     // u32 pair-table, bf16-elem offset

static constexpr int PT_PER_H = 63 * 62;              // [dj][dip] per head
static constexpr int PT_TOTAL = NH * PT_PER_H;        // 46872 u32

#define MFMA16(a,b,c) __builtin_amdgcn_mfma_f32_16x16x32_bf16(a,b,c,0,0,0)

static __device__ inline float fast_exp2(float x) {
#if __has_builtin(__builtin_amdgcn_exp2f)
    return __builtin_amdgcn_exp2f(x);
#else
    return exp2f(x);
#endif
}

// ---------------- merged cast: x transpose + weights + bias pair-table ----------------
__global__ __launch_bounds__(256) void cast_all_kernel(const float* __restrict__ x,
                                                       const float* __restrict__ wq,
                                                       const float* __restrict__ wkv,
                                                       const float* __restrict__ wproj,
                                                       const float* __restrict__ bias_table,
                                                       bf16* __restrict__ xt,
                                                       bf16* __restrict__ wqkv,
                                                       bf16* __restrict__ wp,
                                                       unsigned* __restrict__ PT)
{
    __shared__ bf16 T[64][68];
    const int t = threadIdx.x;
    if (blockIdx.x >= 1344) {
        const int e = (blockIdx.x - 1344) * 256 + t;
        if (e >= PT_TOTAL) return;
        const int h = e / PT_PER_H, rem = e - h * PT_PER_H;
        const int dj = rem / 62, dip = rem - dj * 62;
        bf16 lo = (bf16)(bias_table[(size_t)((dip + 1) * 63 + dj) * NH + h] * LOG2E);
        bf16 hi = (bf16)(bias_table[(size_t)(dip * 63 + dj) * NH + h] * LOG2E);
        PT[e] = (unsigned)__builtin_bit_cast(unsigned short, lo)
              | ((unsigned)__builtin_bit_cast(unsigned short, hi) << 16);
        return;
    }
    if (blockIdx.x >= 768) {
        const size_t i = ((size_t)(blockIdx.x - 768) * 256 + t) * 4;
        if (i >= WQKV_N + WP_N) return;
        const float* src; bf16* dst;
        if (i < (size_t)NC*NC)      { src = wq + i;                     dst = wqkv + i; }
        else if (i < WQKV_N)        { src = wkv + (i - (size_t)NC*NC);  dst = wqkv + i; }
        else                        { src = wproj + (i - WQKV_N);       dst = wp + (i - WQKV_N); }
        float4 v = *(const float4*)src;
        bf16x4 o; o[0] = (bf16)v.x; o[1] = (bf16)v.y; o[2] = (bf16)v.z; o[3] = (bf16)v.w;
        *(bf16x4*)dst = o;
        return;
    }
    const int bid = blockIdx.x;            // b*96 + ct*16 + nt
    const int b = bid / 96, rem = bid % 96, ct = rem >> 4, nt = rem & 15;
    const int c0 = ct * 64, n0 = nt * 64;
    const float* Xb = x + (size_t)b * NC * NN;
    const int nl = t & 63, c4 = (t >> 6) * 4;
#pragma unroll
    for (int i = 0; i < 4; ++i) {
        const int c = c4 + i * 16;
        bf16x4 v;
#pragma unroll
        for (int j = 0; j < 4; ++j)
            v[j] = (bf16)Xb[(size_t)(c0 + c + j) * NN + n0 + nl];  // coalesced over nl
        *(bf16x4*)&T[nl][c] = v;
    }
    __syncthreads();
    const int n = t >> 2;
#pragma unroll
    for (int i = 0; i < 2; ++i) {
        const int cg = (t & 3) * 8 + i * 32;
        bf16x4 a = *(const bf16x4*)&T[n][cg];
        bf16x4 bv = *(const bf16x4*)&T[n][cg + 4];
        bf16x8 vv = __builtin_shufflevector(a, bv, 0, 1, 2, 3, 4, 5, 6, 7);
        *(bf16x8*)&xt[((size_t)b * NN + n0 + n) * NC + c0 + cg] = vv;
    }
}

// ---------------- QKV projection GEMM: 128x128 tile, BK=64, reg-staged ----------
__global__ __launch_bounds__(256) void qkv_gemm_kernel(
    const bf16* __restrict__ W, const bf16* __restrict__ Xt,
    const float* __restrict__ bq, const float* __restrict__ bkv,
    bf16* __restrict__ Qd, bf16* __restrict__ Kd, bf16* __restrict__ Vd)
{
    __shared__ bf16 As[128][72];   // [o][c]
    __shared__ bf16 Bs[128][72];   // [n][c]
    const int t = threadIdx.x;
    const int w = t >> 6, lane = t & 63, g = lane >> 4, l16 = lane & 15;
    const int wm = w >> 1, wn = w & 1;
    const int n0g = blockIdx.x * 128;
    const int b = n0g >> 10, n0 = n0g & 1023;
    const int o0 = blockIdx.y * 128;
    const bf16* Xb = Xt + (size_t)b * NN * NC;

    const int sr = t >> 1, sc2 = (t & 1) * 32;

    f32x4 acc[4][4] = {};

    bf16x8 aw[4], bw[4];
#pragma unroll
    for (int i = 0; i < 4; ++i) {
        aw[i] = *(const bf16x8*)&W [(size_t)(o0 + sr) * NC + sc2 + 8*i];
        bw[i] = *(const bf16x8*)&Xb[(size_t)(n0 + sr) * NC + sc2 + 8*i];
    }

    for (int k0 = 0; k0 < NC; k0 += 64) {
        __syncthreads();                 // B0: prev tile reads done
#pragma unroll
        for (int i = 0; i < 4; ++i) {
            *(bf16x8*)&As[sr][sc2 + 8*i] = aw[i];
            *(bf16x8*)&Bs[sr][sc2 + 8*i] = bw[i];
        }
        __syncthreads();                 // B1: tile visible
        if (k0 + 64 < NC) {              // early-issue next k-tile (hides under MFMA)
#pragma unroll
            for (int i = 0; i < 4; ++i) {
                aw[i] = *(const bf16x8*)&W [(size_t)(o0 + sr) * NC + k0 + 64 + sc2 + 8*i];
                bw[i] = *(const bf16x8*)&Xb[(size_t)(n0 + sr) * NC + k0 + 64 + sc2 + 8*i];
            }
        }
#pragma unroll
        for (int ks = 0; ks < 2; ++ks) {
            bf16x8 a[4], bb[4];
#pragma unroll
            for (int s = 0; s < 4; ++s) {
                a[s]  = *(const bf16x8*)&As[wm*64 + s*16 + l16][ks*32 + g*8];
                bb[s] = *(const bf16x8*)&Bs[wn*64 + s*16 + l16][ks*32 + g*8];
            }
#pragma unroll
            for (int sm = 0; sm < 4; ++sm)
#pragma unroll
                for (int sn = 0; sn < 4; ++sn)
                    acc[sm][sn] = MFMA16(a[sm], bb[sn], acc[sm][sn]);
        }
    }

#pragma unroll
    for (int sm = 0; sm < 4; ++sm)
#pragma unroll
    for (int sn = 0; sn < 4; ++sn) {
        const int col   = n0 + wn*64 + sn*16 + l16;
        const int obase = o0 + wm*64 + sm*16 + g*4;
        f32x4 v = acc[sm][sn];
        if (obase < 384) {
            const int hh = obase >> 5, d = obase & 31;
            bf16x4 o4;
#pragma unroll
            for (int r = 0; r < 4; ++r) o4[r] = (bf16)((v[r] + bq[obase + r]) * QSC);
            *(bf16x4*)&Qd[(((size_t)b*NH + hh)*NN + col)*HD + d] = o4;
        } else if (obase < 768) {
            const int oo = obase - 384; const int hh = oo >> 5, d = oo & 31;
            bf16x4 o4;
#pragma unroll
            for (int r = 0; r < 4; ++r) o4[r] = (bf16)(v[r] + bkv[oo + r]);
            *(bf16x4*)&Kd[(((size_t)b*NH + hh)*NN + col)*HD + d] = o4;
        } else {
            const int oo = obase - 768; const int hh = oo >> 5, d = oo & 31;
#pragma unroll
            for (int r = 0; r < 4; ++r)
                Vd[(((size_t)b*NH + hh)*HD + d + r)*NN + col] = (bf16)(v[r] + bkv[obase - 384 + r]);
        }
    }
}

// ---------------- fused flash attention: split-K, 8 waves x 32 q-rows ----------
// (512,3) blocks-semantics: 3 blocks/CU -> 24 waves/CU, VGPR cap ~85, no spill.
__global__ __launch_bounds__(512, 3) void attn_kernel(
    const bf16* __restrict__ Qg, const bf16* __restrict__ Kg, const bf16* __restrict__ Vg,
    const unsigned* __restrict__ PT, bf16* __restrict__ AOt)
{
    __shared__ __align__(16) char arena[47488];
    bf16 (*KsH)[128][40]   = (bf16 (*)[128][40])arena;             // [half][m][d], 20480B
    bf16 (*VsH)[2][32][72] = (bf16 (*)[2][32][72])(arena + 20480); // [half][sub][d][q], 18432B
    unsigned (*pairTw)[34] = (unsigned (*)[34])(arena + 38912);    // [63][34], 8568B

    const int t = threadIdx.x;
    const int w = t >> 6, lane = t & 63, g = lane >> 4, l16 = lane & 15;
    const int wl = w & 3, hf = w >> 2;

    // XCD-aware swizzle: 768 blocks, 8 XCDs
    const int bid = blockIdx.x;
    const int nid = (bid & 7) * 96 + (bid >> 3);
    const int qt = nid & 7;
    const int hb = nid >> 3;
    const int h = hb % 12, b = hb / 12;

    const bf16* Qb = Qg + ((size_t)(b*NH + h)) * NN * HD;
    const bf16* Kb = Kg + ((size_t)(b*NH + h)) * NN * HD;
    const bf16* Vb = Vg + ((size_t)(b*NH + h)) * HD * NN;

    // staging slots within 256-thread group g2 (== hf for the compute waves)
    const int tl = t & 255, g2 = t >> 8;
    const int kr = tl >> 1, kc2 = (tl & 1) * 16;
    const int vd = tl >> 3, vmb = (tl & 7) * 16;
    int vsub[2], vqa[2];
#pragma unroll
    for (int i = 0; i < 2; ++i) {
        const int vm = vmb + 8*i, vmm = vm & 63;
        vsub[i] = vm >> 6;
        vqa[i]  = ((vmm >> 5) & 1) * 32 + ((vmm >> 2) & 3) * 8 + ((vmm >> 4) & 1) * 4;
    }
    const int mbase = g2 * 512;

    // issue phase-0 loads first (latency hides under pair-table staging)
    bf16x8 sregK[2], sregV[2];
#pragma unroll
    for (int i = 0; i < 2; ++i) {
        sregK[i] = *(const bf16x8*)&Kb[(size_t)(mbase + kr) * HD + kc2 + 8*i];
        sregV[i] = *(const bf16x8*)&Vb[(size_t)vd * NN + mbase + vmb + 8*i];
    }

    const int q0 = qt * 128;
    const bf16x8 qfrag0 = *(const bf16x8*)&Qb[(size_t)(q0 + wl*32      + l16) * HD + g*8];
    const bf16x8 qfrag1 = *(const bf16x8*)&Qb[(size_t)(q0 + wl*32 + 16 + l16) * HD + g*8];

    // stage the precomputed pair-table window (coalesced b32 loads)
    const unsigned* PTh = PT + (size_t)h * PT_PER_H + 4 * qt;
    for (int idx = t; idx < 63 * 34; idx += 512) {
        const int dj = idx / 34, dipl = idx - dj * 34;
        pairTw[dj][dipl] = PTh[dj * 62 + dipl];
    }
    // visible after the loop's first two barriers

    const unsigned* twp = &pairTw[0][0];
    const int rowD1 = (l16 + 31 - 4*g) * 34;

    bf16x8 vones;
#pragma unroll
    for (int e = 0; e < 8; ++e) vones[e] = (bf16)1.0f;

    f32x4 oacc0[2] = {}, oacc1[2] = {};
    f32x4 oacc_l0 = {}, oacc_l1 = {};

    for (int ph = 0; ph < 4; ++ph) {
        __syncthreads();                              // B0: all reads of prev phase done
#pragma unroll
        for (int i = 0; i < 2; ++i) {
            *(bf16x8*)&KsH[g2][kr][kc2 + 8*i] = sregK[i];
            bf16x4 vlo = __builtin_shufflevector(sregV[i], sregV[i], 0, 1, 2, 3);
            bf16x4 vhi = __builtin_shufflevector(sregV[i], sregV[i], 4, 5, 6, 7);
            *(bf16x4*)&VsH[g2][vsub[i]][vd][vqa[i]]     = vlo;
            *(bf16x4*)&VsH[g2][vsub[i]][vd][vqa[i] + 8] = vhi;
        }
        __syncthreads();                              // B1: phase tiles visible
        if (ph < 3) {                                 // T14: issue next phase early
            const int m1 = mbase + (ph + 1) * 128;
#pragma unroll
            for (int i = 0; i < 2; ++i) {
                sregK[i] = *(const bf16x8*)&Kb[(size_t)(m1 + kr) * HD + kc2 + 8*i];
                sregV[i] = *(const bf16x8*)&Vb[(size_t)vd * NN + m1 + vmb + 8*i];
            }
        }

#pragma unroll
        for (int sub = 0; sub < 2; ++sub) {
            const int it = hf * 8 + 2 * ph + sub;     // global 64-key subtile index
            const bf16 (*Vsp)[72] = VsH[hf][sub];
            const int dipl = wl + 30 - 2*it;          // in [0,33]
            const unsigned* pD1 = twp + rowD1 + dipl;

            // shared bias rows: D0 = D1-16 rows, D2 = D1+16 rows (stride 34 u32)
            f32x4 b00, b01, b02, b03, b10, b12;       // b11=b00, b13=b02
#pragma unroll
            for (int r = 0; r < 4; ++r) {
                const unsigned d1w = pD1[-34 * r];
                const unsigned d0w = pD1[-34 * r - 544];
                const unsigned d2w = pD1[-34 * r + 544];
                b00[r] = __uint_as_float(d1w << 16);
                b02[r] = __uint_as_float(d1w & 0xFFFF0000u);
                b01[r] = __uint_as_float(d0w << 16);
                b03[r] = __uint_as_float(d0w & 0xFFFF0000u);
                b10[r] = __uint_as_float(d2w << 16);
                b12[r] = __uint_as_float(d2w & 0xFFFF0000u);
            }
            f32x4 bacc0[4] = {b00, b01, b02, b03};
            f32x4 bacc1[4] = {b10, b00, b12, b02};

            bf16x8 pa0[2], pa1[2];
#pragma unroll
            for (int sc = 0; sc < 4; ++sc) {
                bf16x8 kf = *(const bf16x8*)&KsH[hf][sub*64 + sc*16 + l16][g*8];
                f32x4 z0 = MFMA16(kf, qfrag0, bacc0[sc]);   // S^T + bias, frag0
                f32x4 z1 = MFMA16(kf, qfrag1, bacc1[sc]);   // frag1
                const int kc = sc >> 1, hl = (sc & 1) * 4;
#pragma unroll
                for (int r = 0; r < 4; ++r) {
                    pa0[kc][hl + r] = (bf16)fast_exp2(z0[r]);
                    pa1[kc][hl + r] = (bf16)fast_exp2(z1[r]);
                }
            }

            // PV: slot k=8g+4sh+r <-> m=32kc+16sh+4g+r ; vf shared across frags
#pragma unroll
            for (int kc = 0; kc < 2; ++kc) {
#pragma unroll
                for (int ds = 0; ds < 2; ++ds) {
                    bf16x8 vf = *(const bf16x8*)&Vsp[ds*16 + l16][kc*32 + 8*g];
                    oacc0[ds] = MFMA16(pa0[kc], vf, oacc0[ds]);
                    oacc1[ds] = MFMA16(pa1[kc], vf, oacc1[ds]);
                }
                oacc_l0 = MFMA16(pa0[kc], vones, oacc_l0);
                oacc_l1 = MFMA16(pa1[kc], vones, oacc_l1);
            }
        }
    }

    // merge halves: waves 4-7 publish partials; waves 0-3 combine + epilogue
    __syncthreads();                                  // all LDS reads of last phase done
    f32x4* mbuf = (f32x4*)arena;                      // 6 x [4][64] f32x4 = 24576B
    const int sb = wl * 64 + lane;
    if (hf == 1) {
        mbuf[0*256 + sb] = oacc0[0]; mbuf[1*256 + sb] = oacc0[1];
        mbuf[2*256 + sb] = oacc1[0]; mbuf[3*256 + sb] = oacc1[1];
        mbuf[4*256 + sb] = oacc_l0;  mbuf[5*256 + sb] = oacc_l1;
    }
    __syncthreads();
    if (hf == 0) {
        oacc0[0] += mbuf[0*256 + sb]; oacc0[1] += mbuf[1*256 + sb];
        oacc1[0] += mbuf[2*256 + sb]; oacc1[1] += mbuf[3*256 + sb];
        oacc_l0  += mbuf[4*256 + sb]; oacc_l1  += mbuf[5*256 + sb];

        float rin0[4], rin1[4];
#pragma unroll
        for (int r = 0; r < 4; ++r) {
            rin0[r] = 1.0f / oacc_l0[r];
            rin1[r] = 1.0f / oacc_l1[r];
        }
        const int nrow0 = q0 + wl*32 + g*4;
#pragma unroll
        for (int ds = 0; ds < 2; ++ds) {
            const int c = h*HD + ds*16 + l16;
#pragma unroll
            for (int r = 0; r < 4; ++r) {
                AOt[((size_t)b*NN + nrow0 + r)      * NC + c] = (bf16)(oacc0[ds][r] * rin0[r]);
                AOt[((size_t)b*NN + nrow0 + 16 + r) * NC + c] = (bf16)(oacc1[ds][r] * rin1[r]);
            }
        }
    }
}

// ---------------- output projection GEMM (64x128 tile, reg-prefetch) ----------------
__global__ __launch_bounds__(256) void proj_gemm_kernel(
    const bf16* __restrict__ W, const bf16* __restrict__ AOt,
    const float* __restrict__ bproj, float* __restrict__ out)
{
    __shared__ bf16 As[64][40];
    __shared__ bf16 Bs[128][40];
    const int t = threadIdx.x;
    const int w = t >> 6, lane = t & 63, g = lane >> 4, l16 = lane & 15;
    const int wm = w >> 1, wn = w & 1;
    const int n0g = blockIdx.x * 128;
    const int b = n0g >> 10, n0 = n0g & 1023;
    const int o0 = blockIdx.y * 64;
    const bf16* Ab = AOt + (size_t)b * NN * NC;

    const int ar = t >> 2, ac = (t & 3) * 8;

    f32x4 acc[2][4] = {};

    bf16x8 aw = *(const bf16x8*)&W[(size_t)(o0 + ar) * NC + ac];
    bf16x8 bw[2];
#pragma unroll
    for (int i = 0; i < 2; ++i) {
        const int s = t + i * 256, r = s >> 2, cc = (s & 3) * 8;
        bw[i] = *(const bf16x8*)&Ab[(size_t)(n0 + r) * NC + cc];
    }

    for (int k0 = 0; k0 < NC; k0 += 32) {
        __syncthreads();
        *(bf16x8*)&As[ar][ac] = aw;
#pragma unroll
        for (int i = 0; i < 2; ++i) {
            const int s = t + i * 256, r = s >> 2, cc = (s & 3) * 8;
            *(bf16x8*)&Bs[r][cc] = bw[i];
        }
        __syncthreads();
        if (k0 + 32 < NC) {
            aw = *(const bf16x8*)&W[(size_t)(o0 + ar) * NC + k0 + 32 + ac];
#pragma unroll
            for (int i = 0; i < 2; ++i) {
                const int s = t + i * 256, r = s >> 2, cc = (s & 3) * 8;
                bw[i] = *(const bf16x8*)&Ab[(size_t)(n0 + r) * NC + k0 + 32 + cc];
            }
        }
        bf16x8 a0 = *(const bf16x8*)&As[wm*32      + l16][g*8];
        bf16x8 a1 = *(const bf16x8*)&As[wm*32 + 16 + l16][g*8];
#pragma unroll
        for (int sn = 0; sn < 4; ++sn) {
            bf16x8 bf = *(const bf16x8*)&Bs[wn*64 + sn*16 + l16][g*8];
            acc[0][sn] = MFMA16(a0, bf, acc[0][sn]);
            acc[1][sn] = MFMA16(a1, bf, acc[1][sn]);
        }
    }

#pragma unroll
    for (int sm = 0; sm < 2; ++sm)
#pragma unroll
    for (int sn = 0; sn < 4; ++sn) {
        const int col   = n0 + wn*64 + sn*16 + l16;
        const int obase = o0 + wm*32 + sm*16 + g*4;
        f32x4 v = acc[sm][sn];
#pragma unroll
        for (int r = 0; r < 4; ++r)
            out[((size_t)b*NC + obase + r)*NN + col] = v[r] + bproj[obase + r];
    }
}

extern "C" void kernel_launch(void* const* d_in, const int* in_sizes, int n_in,
                              void* d_out, int out_size, void* d_ws, size_t ws_size,
                              hipStream_t stream)
{
    const float* x          = (const float*)d_in[0];
    const float* wq         = (const float*)d_in[1];
    const float* bq         = (const float*)d_in[2];
    const float* wkv        = (const float*)d_in[3];
    const float* bkv        = (const float*)d_in[4];
    const float* wproj      = (const float*)d_in[5];
    const float* bproj      = (const float*)d_in[6];
    const float* bias_table = (const float*)d_in[7];
    // d_in[8] = rel_index: unused (bias index computed arithmetically in-kernel)
    float* out = (float*)d_out;

    bf16* wsb  = (bf16*)d_ws;
    bf16* Xt   = wsb + XT_OFF;
    bf16* Wqkv = wsb + WQKV_OFF;
    bf16* Wp   = wsb + WP_OFF;
    bf16* Qd   = wsb + Q_OFF;
    bf16* Kd   = wsb + K_OFF;
    bf16* Vd   = wsb + V_OFF;
    bf16* AOt  = wsb + AO_OFF;
    unsigned* PT = (unsigned*)(wsb + PT_OFF);

    const int ptBlocks = (PT_TOTAL + 255) / 256;       // 184
    cast_all_kernel<<<dim3(768 + 576 + ptBlocks), 256, 0, stream>>>(
        x, wq, wkv, wproj, bias_table, Xt, Wqkv, Wp, PT);
    qkv_gemm_kernel<<<dim3(64, 9), 256, 0, stream>>>(Wqkv, Xt, bq, bkv, Qd, Kd, Vd);
    attn_kernel<<<dim3(768), 512, 0, stream>>>(Qd, Kd, Vd, PT, AOt);
    proj_gemm_kernel<<<dim3(64, 6), 256, 0, stream>>>(Wp, AOt, bproj, out);
}